// Round 4
// baseline (195.741 us; speedup 1.0000x reference)
//
#include <hip/hip_runtime.h>

#define U_CNT 16384
#define I_CNT 8192
#define DIM 64
#define BAND 16                   // output rows per gemm block
#define CHUNK 256                 // output cols per chunk iteration
#define NCHUNK (I_CNT / CHUNK)    // 32
#define LDS_STRIDE 68             // floats; 68 % 32 == 4 -> 2-way conflicts only (free)
#define NEG_LOG2E (-1.4426950408889634f)

typedef __bf16 bf16x8 __attribute__((ext_vector_type(8)));
typedef float f32x4 __attribute__((ext_vector_type(4)));

__device__ __forceinline__ unsigned short f32_to_bf16_rtn(float f) {
    unsigned int b = __float_as_uint(f);
    b += 0x7fffu + ((b >> 16) & 1u);
    return (unsigned short)(b >> 16);
}

// Fused prep + pfull (one launch, no bounds-array dependency):
//   blocks [0, 2048):    Q1 -> bf16 conversion (covers I_CNT*DIM = 524288).
//   blocks [2048, 6144): one wave per user; binary-search segment bounds in
//                        sorted seg_ids, sum Q2 rows (lane = dim), scale by
//                        rsqrt(count), add P, write bf16 A-matrix.
__global__ __launch_bounds__(256) void prep_pfull_kernel(
    const float* __restrict__ Q1, unsigned short* __restrict__ Q1bf,
    const float* __restrict__ Q2, const float* __restrict__ P,
    const int* __restrict__ items, const int* __restrict__ segs,
    int nnz, unsigned short* __restrict__ Pbf)
{
    if (blockIdx.x < 2048) {
        int i = blockIdx.x * 256 + threadIdx.x;
        Q1bf[i] = f32_to_bf16_rtn(Q1[i]);
        return;
    }
    int u = ((blockIdx.x - 2048) * 256 + threadIdx.x) >> 6;
    int lane = threadIdx.x & 63;
    if (u >= U_CNT) return;

    int lo = 0, hi = nnz;
    while (lo < hi) { int m = (lo + hi) >> 1; if (segs[m] < u) lo = m + 1; else hi = m; }
    int start = lo;
    hi = nnz;
    while (lo < hi) { int m = (lo + hi) >> 1; if (segs[m] <= u) lo = m + 1; else hi = m; }
    int end = lo;

    float s = 0.f;
    int j = start;
    for (; j + 3 < end; j += 4) {
        int i0 = items[j], i1 = items[j + 1], i2 = items[j + 2], i3 = items[j + 3];
        float v0 = Q2[i0 * DIM + lane];
        float v1 = Q2[i1 * DIM + lane];
        float v2 = Q2[i2 * DIM + lane];
        float v3 = Q2[i3 * DIM + lane];
        s += (v0 + v1) + (v2 + v3);
    }
    for (; j < end; ++j) s += Q2[items[j] * DIM + lane];

    int cnt = end - start;              // guaranteed >= 1
    float val = s * rsqrtf((float)cnt) + P[u * DIM + lane];
    Pbf[u * DIM + lane] = f32_to_bf16_rtn(val);
}

// Band-sweep GEMM + sigmoid epilogue, nontemporal output stores.
// Block = 16-row band x all 8192 cols, 32 chunks of 256 cols, phase-staggered
// per block. Wave wid owns a 64-col sub-band. Chunk loop unrolled x2 with
// alternating B-register buffers so next chunk's L2 loads fly during the
// current epilogue. Output stores are NONTEMPORAL: no L2/L3 write-allocate,
// so HBM sees the (already linearized) program store order instead of
// Infinity-Cache eviction order.
__global__ __launch_bounds__(256) void gemm_sig_kernel(
    const unsigned short* __restrict__ Abf, const unsigned short* __restrict__ Bbf,
    const float* __restrict__ bu, const float* __restrict__ bi,
    float* __restrict__ out)
{
    const int lane = threadIdx.x & 63;
    const int wid  = threadIdx.x >> 6;
    const int r = lane & 15, g = lane >> 4;
    const int band = blockIdx.x * BAND;

    __shared__ float lds_all[4][BAND * LDS_STRIDE];
    float* lds = lds_all[wid];              // per-wave private region

    bf16x8 a[2];
#pragma unroll
    for (int ks = 0; ks < 2; ++ks)
        a[ks] = *reinterpret_cast<const bf16x8*>(&Abf[(band + r) * DIM + ks * 32 + g * 8]);

    float bu_g[4];                          // pre-biased with +0.05
#pragma unroll
    for (int j = 0; j < 4; ++j) bu_g[j] = bu[band + g * 4 + j] + 0.05f;

    const int c0 = (blockIdx.x * 7) & (NCHUNK - 1);

    bf16x8 bA[4][2], bB[4][2];
    float biA[4], biB[4];

#define LOAD_B(BUF, BIF, CC)                                                   \
    {                                                                          \
        const int c_ = ((CC) + c0) & (NCHUNK - 1);                             \
        const int col0_ = c_ * CHUNK + wid * 64;                               \
        _Pragma("unroll")                                                      \
        for (int nf = 0; nf < 4; ++nf) {                                       \
            BIF[nf] = bi[col0_ + nf * 16 + r];                                 \
            _Pragma("unroll")                                                  \
            for (int ks = 0; ks < 2; ++ks)                                     \
                BUF[nf][ks] = *reinterpret_cast<const bf16x8*>(                \
                    &Bbf[(col0_ + nf * 16 + r) * DIM + ks * 32 + g * 8]);      \
        }                                                                      \
    }

#define COMPUTE_STORE(BUF, BIF, CC)                                            \
    {                                                                          \
        const int c_ = ((CC) + c0) & (NCHUNK - 1);                             \
        const int col0_ = c_ * CHUNK + wid * 64;                               \
        f32x4 acc[4] = {};                                                     \
        _Pragma("unroll")                                                      \
        for (int ks = 0; ks < 2; ++ks)                                         \
            _Pragma("unroll")                                                  \
            for (int nf = 0; nf < 4; ++nf)                                     \
                acc[nf] = __builtin_amdgcn_mfma_f32_16x16x32_bf16(             \
                    a[ks], BUF[nf][ks], acc[nf], 0, 0, 0);                     \
        _Pragma("unroll")                                                      \
        for (int nf = 0; nf < 4; ++nf)                                         \
            _Pragma("unroll")                                                  \
            for (int j = 0; j < 4; ++j) {                                      \
                float x = (acc[nf][j] + bu_g[j] + BIF[nf]) * NEG_LOG2E;        \
                float e = __builtin_amdgcn_exp2f(x);                           \
                float v = 5.f * __builtin_amdgcn_rcpf(1.f + e);                \
                lds[(g * 4 + j) * LDS_STRIDE + nf * 16 + r] = v;               \
            }                                                                  \
        _Pragma("unroll")                                                      \
        for (int i = 0; i < 4; ++i) {                                          \
            const int row = i * 4 + g;                                         \
            f32x4 v = *reinterpret_cast<const f32x4*>(                         \
                &lds[row * LDS_STRIDE + r * 4]);                               \
            __builtin_nontemporal_store(v, reinterpret_cast<f32x4*>(           \
                &out[(size_t)(band + row) * I_CNT + col0_ + r * 4]));          \
        }                                                                      \
    }

    LOAD_B(bA, biA, 0)
    for (int cc = 0; cc < NCHUNK; cc += 2) {
        LOAD_B(bB, biB, cc + 1)
        COMPUTE_STORE(bA, biA, cc)
        LOAD_B(bA, biA, cc + 2)        // cc+2==NCHUNK wraps to chunk c0: harmless
        COMPUTE_STORE(bB, biB, cc + 1)
    }
#undef LOAD_B
#undef COMPUTE_STORE
}

extern "C" void kernel_launch(void* const* d_in, const int* in_sizes, int n_in,
                              void* d_out, int out_size, void* d_ws, size_t ws_size,
                              hipStream_t stream)
{
    const float* Q1 = (const float*)d_in[0];
    const float* Q2 = (const float*)d_in[1];
    const float* P  = (const float*)d_in[2];
    const float* bu = (const float*)d_in[3];
    const float* bi = (const float*)d_in[4];
    const int* items = (const int*)d_in[5];
    const int* segs  = (const int*)d_in[6];
    const int nnz = in_sizes[5];

    unsigned short* Pbf  = (unsigned short*)d_ws;            // 2 MB
    unsigned short* Q1bf = Pbf + U_CNT * DIM;                // 1 MB

    prep_pfull_kernel<<<2048 + U_CNT / 4, 256, 0, stream>>>(
        Q1, Q1bf, Q2, P, items, segs, nnz, Pbf);
    gemm_sig_kernel<<<U_CNT / BAND, 256, 0, stream>>>(Pbf, Q1bf, bu, bi, (float*)d_out);
}